// Round 8
// baseline (217.607 us; speedup 1.0000x reference)
//
#include <hip/hip_runtime.h>

// Rainfusion blockwise sparse attention. f32 in/out; fp16 MFMA (32x32x16) inside.
// Fixed-m softmax (m=0), scale folded into Q regs. Prep pre-permutes K,V to padded
// fp16 tiles; flash stages via global_load_lds, selection fused (wave 0), combine
// fused (last heavy chunk per group via device-scope atomic). h = blockIdx%8 XCD affinity.

typedef __attribute__((ext_vector_type(8))) _Float16 half8;
typedef __attribute__((ext_vector_type(4))) _Float16 half4;
typedef __attribute__((ext_vector_type(4))) float float4v;
typedef __attribute__((ext_vector_type(16))) float float16v;

#define KROW 136   // shorts per K row: 128 dims + 8 pad
#define VROW 72    // shorts per V^T row: 64 toks + 8 pad
#define PROW 72

__device__ __forceinline__ int orig_pos(int j) {
    if (j >= 3840) return (j < 4224) ? (j - 3840) : j;
    int blk = j >> 7;
    int r   = j & 127;
    int f   = blk / 6;
    int rem = blk - f * 6;
    int b2  = rem / 3;
    int e   = rem - b2 * 3;
    int a   = r >> 6;
    int c   = (r >> 3) & 7;
    int g   = r & 7;
    return 384 + (f * 2 + a) * 384 + (b2 * 8 + c) * 24 + e * 8 + g;
}

__device__ __forceinline__ void cp16(const void* g, void* l) {
    __builtin_amdgcn_global_load_lds((const __attribute__((address_space(1))) void*)g,
                                     (__attribute__((address_space(3))) void*)l, 16, 0, 0);
}

__device__ __forceinline__ short h16(float x) {
    union { _Float16 hf; short s; } cv;
    cv.hf = (_Float16)x;
    return cv.s;
}

// ---------------- prep: grid 576 = (h, kb, sub). conv 64 toks + one pooled sum ----------------
__global__ __launch_bounds__(256) void prep_kernel(const float* __restrict__ q,
                                                   const float* __restrict__ k,
                                                   const float* __restrict__ v,
                                                   short* __restrict__ Kc,
                                                   unsigned* __restrict__ Vt32,
                                                   float* __restrict__ qp,
                                                   float* __restrict__ kp) {
    __shared__ short Vs[64 * KROW];
    __shared__ float Rs[8 * 128];
    int bx  = blockIdx.x;
    int tid = threadIdx.x;
    int sub = bx & 1;
    int kb  = (bx >> 1) % 36;
    int h   = bx / 72;

    { // conv: 64 toks -> Kc fp16 + Vs (LDS). 8 lanes x consecutive float4 per row.
        int lr = tid >> 3;
        int ld = (tid & 7) << 2;
#pragma unroll
        for (int pass = 0; pass < 2; ++pass) {
            int lt  = pass * 32 + lr;
            int tok = sub * 64 + lt;
            int op  = orig_pos(kb * 128 + tok);
            const float* kr = k + ((size_t)op * 8 + h) * 128;
            const float* vr = v + ((size_t)op * 8 + h) * 128;
            short* ko = Kc + ((size_t)(h * 36 + kb) * 128 + tok) * KROW;
#pragma unroll
            for (int j = 0; j < 4; ++j) {
                int d = ld + j * 32;
                float4v xk = *reinterpret_cast<const float4v*>(kr + d);
                float4v xv = *reinterpret_cast<const float4v*>(vr + d);
                half4 hk, hv;
#pragma unroll
                for (int i = 0; i < 4; ++i) { hk[i] = (_Float16)xk[i]; hv[i] = (_Float16)xv[i]; }
                *reinterpret_cast<half4*>(ko + d) = hk;
                *reinterpret_cast<half4*>(&Vs[lt * KROW + d]) = hv;
            }
        }
    }

    { // pooled sum: sub=0 -> K, sub=1 -> Q
        const float* arr = sub ? q : k;
        int dq = (tid & 31) << 2;
        int g  = tid >> 5;
        float4v acc = {0.f, 0.f, 0.f, 0.f};
        for (int t = g; t < 128; t += 8) {
            int op = orig_pos(kb * 128 + t);
            float4v x = *reinterpret_cast<const float4v*>(arr + ((size_t)op * 8 + h) * 128 + dq);
            acc[0] += x[0]; acc[1] += x[1]; acc[2] += x[2]; acc[3] += x[3];
        }
#pragma unroll
        for (int i = 0; i < 4; ++i) Rs[g * 128 + dq + i] = acc[i];
    }
    __syncthreads();

    { // V^T -> Vt [h][kb][sub][dim][VROW/2], dword-packed token pairs
        const unsigned short* Vsu = (const unsigned short*)Vs;
        unsigned* vo = Vt32 + (size_t)((h * 36 + kb) * 2 + sub) * 128 * (VROW / 2);
#pragma unroll
        for (int it = 0; it < 16; ++it) {
            int i   = it * 256 + tid;
            int tw  = i & 31;
            int dim = i >> 5;
            unsigned lo = Vsu[(2 * tw) * KROW + dim];
            unsigned hi = Vsu[(2 * tw + 1) * KROW + dim];
            vo[dim * (VROW / 2) + tw] = (hi << 16) | lo;
        }
    }

    if (tid < 128) {
        float s = 0.f;
#pragma unroll
        for (int g = 0; g < 8; ++g) s += Rs[g * 128 + tid];
        float* outp = sub ? qp : kp;
        outp[(h * 36 + kb) * 128 + tid] = s * (1.f / 128.f);
    }
}

// ---------------- flash (32x32x16 f16) ----------------
// grid 432: 0..191 heavy chunks (h=t&7, qbh=(t>>3)>>2, chunk=(t>>3)&3; 9 kb each),
// 192..431 light (h=t&7, qb=(t-192)>>3). Wave = 32 q-rows, wg = full 128-row qb.
__global__ __launch_bounds__(256, 2) void flash_kernel(const float* __restrict__ q,
                                                       const short* __restrict__ Kc,
                                                       const short* __restrict__ Vt,
                                                       const float* __restrict__ qp,
                                                       const float* __restrict__ kp,
                                                       float* __restrict__ out,
                                                       float* __restrict__ pO,
                                                       float* __restrict__ pL,
                                                       int* __restrict__ cnt) {
    __shared__ __align__(16) short Ks[64 * KROW];      // 17408 B
    __shared__ __align__(16) short Vsh[128 * VROW];    // 18432 B
    __shared__ __align__(16) short Ph[4 * 32 * PROW];  // 18432 B
    __shared__ int Ls[40];

    int t = blockIdx.x;
    int h, qb, qbh = 0, nkb = 0, kbase = 0, task = -1, grp = -1;
    bool heavy = (t < 192);
    if (heavy) {
        h = t & 7;
        int rest = t >> 3;         // 0..23
        qbh = rest >> 2;
        int chunk = rest & 3;
        qb = 30 + qbh; nkb = 9; kbase = chunk * 9;
        task = t; grp = qbh * 8 + h;
    } else {
        int t2 = t - 192;
        h = t2 & 7; qb = t2 >> 3;  // 0..29
    }

    int tid = threadIdx.x, wave = tid >> 6, lane = tid & 63;
    int m32 = lane & 31, half = lane >> 5;

    // Q A-frags: A[m=lane&31][k=half*8+j], kc steps of 16 dims; kScale folded in.
    constexpr float kScale = 0.08838834764831845f * 1.4426950408889634f;
    const float* qrp = q + ((size_t)orig_pos(qb * 128 + wave * 32 + m32) * 8 + h) * 128 + half * 8;
    half8 aq[8];
#pragma unroll
    for (int kc = 0; kc < 8; ++kc) {
        float4v x0 = *reinterpret_cast<const float4v*>(qrp + kc * 16);
        float4v x1 = *reinterpret_cast<const float4v*>(qrp + kc * 16 + 4);
#pragma unroll
        for (int j = 0; j < 4; ++j) {
            aq[kc][j]     = (_Float16)(x0[j] * kScale);
            aq[kc][4 + j] = (_Float16)(x1[j] * kScale);
        }
    }

    // fused selection (light only; wave 0) — same float ordering as before
    if (!heavy && wave == 0) {
        float s = -1e30f;
        if (lane < 36) {
            const float4v* qv = (const float4v*)(qp + (h * 36 + qb) * 128);
            const float4v* kv = (const float4v*)(kp + (h * 36 + lane) * 128);
            float acc = 0.f;
            for (int i = 0; i < 32; ++i) {
                float4v a = qv[i], b = kv[i];
                acc += a[0] * b[0] + a[1] * b[1] + a[2] * b[2] + a[3] * b[3];
            }
            s = acc;
        }
        float tmp = s;
        float thr = 0.f;
        for (int i = 0; i < 4; ++i) {
            float mx = tmp;
            for (int off = 1; off < 64; off <<= 1) mx = fmaxf(mx, __shfl_xor(mx, off));
            thr = mx;
            unsigned long long bal = __ballot(tmp == mx);
            int low = __ffsll(bal) - 1;
            if (lane == low) tmp = -3e38f;
        }
        bool keep = (lane < 36) && ((s >= thr) || (lane >= 30));
        unsigned long long mk = __ballot(keep);
        if (lane == 0) Ls[0] = __popcll(mk);
        if (keep) {
            int pos = __popcll(mk & ((1ull << lane) - 1ull));
            Ls[1 + pos] = lane;
        }
    }
    __syncthreads();
    if (!heavy) nkb = Ls[0];

    float16v oc[4];
    float l_r[16];
#pragma unroll
    for (int dn = 0; dn < 4; ++dn)
#pragma unroll
        for (int i = 0; i < 16; ++i) oc[dn][i] = 0.f;
#pragma unroll
    for (int r = 0; r < 16; ++r) l_r[r] = 0.f;

    short* Phw = Ph + wave * (32 * PROW);

    int ntile = nkb * 2;
    for (int it = 0; it < ntile; ++it) {
        int kb  = heavy ? (kbase + (it >> 1)) : Ls[1 + (it >> 1)];
        int sub = it & 1;
        const char* gK = (const char*)(Kc + ((size_t)((h * 36 + kb) * 128) + sub * 64) * KROW);
        const char* gV = (const char*)(Vt + (size_t)((h * 36 + kb) * 2 + sub) * 128 * VROW);

        __syncthreads();
        {
            char* lK = (char*)Ks;
            char* lV = (char*)Vsh;
            int off = lane * 16;
            for (int c = wave; c < 35; c += 4) {
                if (c < 17) cp16(gK + c * 1024 + off, lK + c * 1024 + off);
                else        cp16(gV + (c - 17) * 1024 + off, lV + (c - 17) * 1024 + off);
            }
        }
        __syncthreads();

        // S = Q K^T (64 tokens = 2 n-tiles of 32), B[k][n]: n=tok=nt*32+m32, k=kc*16+half*8+j
        float16v s0, s1;
#pragma unroll
        for (int i = 0; i < 16; ++i) { s0[i] = 0.f; s1[i] = 0.f; }
#pragma unroll
        for (int kc = 0; kc < 8; ++kc) {
            half8 b0 = *reinterpret_cast<const half8*>(&Ks[m32 * KROW + kc * 16 + half * 8]);
            half8 b1 = *reinterpret_cast<const half8*>(&Ks[(32 + m32) * KROW + kc * 16 + half * 8]);
            s0 = __builtin_amdgcn_mfma_f32_32x32x16_f16(aq[kc], b0, s0, 0, 0, 0);
            s1 = __builtin_amdgcn_mfma_f32_32x32x16_f16(aq[kc], b1, s1, 0, 0, 0);
        }

        // fixed-m softmax + P write (C-layout: row=(r&3)+8*(r>>2)+4*half, col=nt*32+m32)
#pragma unroll
        for (int r = 0; r < 16; ++r) {
            int rowl = (r & 3) + 8 * (r >> 2) + 4 * half;
            float p0 = exp2f(s0[r]);
            float p1 = exp2f(s1[r]);
            l_r[r] += p0 + p1;
            Phw[rowl * PROW + m32]      = h16(p0);
            Phw[rowl * PROW + 32 + m32] = h16(p1);
        }

        // P A-frags: A[m=m32][k=kc2*16+half*8+j]
        half8 ap[4];
#pragma unroll
        for (int kc2 = 0; kc2 < 4; ++kc2)
            ap[kc2] = *reinterpret_cast<const half8*>(&Phw[m32 * PROW + kc2 * 16 + half * 8]);

        // O += P V : B[k=tok][n=dim]: n=dn*32+m32, k=kc2*16+half*8+j (V^T rows)
#pragma unroll
        for (int kc2 = 0; kc2 < 4; ++kc2)
#pragma unroll
            for (int dn = 0; dn < 4; ++dn) {
                half8 bv = *reinterpret_cast<const half8*>(&Vsh[(dn * 32 + m32) * VROW + kc2 * 16 + half * 8]);
                oc[dn] = __builtin_amdgcn_mfma_f32_32x32x16_f16(ap[kc2], bv, oc[dn], 0, 0, 0);
            }
    }

    // l: reduce across the 32 lanes holding each row's columns (xor masks stay in half)
#pragma unroll
    for (int r = 0; r < 16; ++r)
        for (int sh = 1; sh < 32; sh <<= 1) l_r[r] += __shfl_xor(l_r[r], sh);

    if (!heavy) {
#pragma unroll
        for (int r = 0; r < 16; ++r) {
            int rowl = (r & 3) + 8 * (r >> 2) + 4 * half;
            size_t base = ((size_t)orig_pos(qb * 128 + wave * 32 + rowl) * 8 + h) * 128;
            float inv = 1.f / l_r[r];
#pragma unroll
            for (int dn = 0; dn < 4; ++dn)
                out[base + dn * 32 + m32] = oc[dn][r] * inv;
        }
    } else {
        float* po = pO + (size_t)task * 16384;
#pragma unroll
        for (int r = 0; r < 16; ++r) {
            int rowl = (r & 3) + 8 * (r >> 2) + 4 * half;
            int row  = wave * 32 + rowl;
#pragma unroll
            for (int dn = 0; dn < 4; ++dn)
                po[row * 128 + dn * 32 + m32] = oc[dn][r];
            if (m32 == 0) pL[task * 128 + row] = l_r[r];
        }
        __threadfence();   // release partials (device scope)
        __syncthreads();
        if (tid == 0) Ls[0] = (atomicAdd(&cnt[grp], 1) == 3) ? 1 : 0;
        __syncthreads();
        if (Ls[0]) {       // last chunk of this (h,qbh) group: combine all 4
            __threadfence();
            int t0 = ((qbh * 4 + 0) << 3) | h;
            int t1 = ((qbh * 4 + 1) << 3) | h;
            int t2 = ((qbh * 4 + 2) << 3) | h;
            int t3 = ((qbh * 4 + 3) << 3) | h;
            int row = tid >> 1;
            int d0  = (tid & 1) * 64;
            float l = pL[t0 * 128 + row] + pL[t1 * 128 + row] + pL[t2 * 128 + row] + pL[t3 * 128 + row];
            float inv = 1.f / l;
            float* ob = out + ((size_t)orig_pos(qb * 128 + row) * 8 + h) * 128 + d0;
            const float* p0 = pO + (size_t)t0 * 16384 + row * 128 + d0;
            const float* p1 = pO + (size_t)t1 * 16384 + row * 128 + d0;
            const float* p2 = pO + (size_t)t2 * 16384 + row * 128 + d0;
            const float* p3 = pO + (size_t)t3 * 16384 + row * 128 + d0;
#pragma unroll
            for (int i = 0; i < 16; ++i) {
                float4v a = *reinterpret_cast<const float4v*>(p0 + i * 4);
                float4v b = *reinterpret_cast<const float4v*>(p1 + i * 4);
                float4v c = *reinterpret_cast<const float4v*>(p2 + i * 4);
                float4v d = *reinterpret_cast<const float4v*>(p3 + i * 4);
                float4v o;
#pragma unroll
                for (int j = 0; j < 4; ++j) o[j] = (a[j] + b[j] + c[j] + d[j]) * inv;
                *reinterpret_cast<float4v*>(ob + i * 4) = o;
            }
        }
    }
}

extern "C" void kernel_launch(void* const* d_in, const int* in_sizes, int n_in,
                              void* d_out, int out_size, void* d_ws, size_t ws_size,
                              hipStream_t stream) {
    const float* q = (const float*)d_in[0];
    const float* k = (const float*)d_in[1];
    const float* v = (const float*)d_in[2];
    float* out = (float*)d_out;

    char* w = (char*)d_ws;
    short* Kc  = (short*)(w);                 // 10,027,008 B
    short* Vt  = (short*)(w + 10027008);      // 10,616,832 B
    float* qp  = (float*)(w + 20643840);      // 147,456 B
    float* kp  = (float*)(w + 20791296);      // 147,456 B
    float* pL  = (float*)(w + 20938752);      // 192*128*4 = 98,304 B
    int*   cnt = (int*)  (w + 21037056);      // 256 B
    float* pO  = (float*)(w + 21037312);      // 192*16384*4 = 12,582,912 B (total ~33.6 MB)

    hipMemsetAsync(cnt, 0, 256, stream);
    prep_kernel<<<dim3(576), dim3(256), 0, stream>>>(q, k, v, Kc, (unsigned*)Vt, qp, kp);
    flash_kernel<<<dim3(432), dim3(256), 0, stream>>>(q, Kc, Vt, qp, kp, out, pO, pL, cnt);
}